// Round 4
// baseline (231.197 us; speedup 1.0000x reference)
//
#include <hip/hip_runtime.h>
#include <math.h>

// Problem constants (from reference)
#define MSEG  4096     // number of graphs / segments
#define NNODE 262144   // total nodes
#define DDIM  128      // d_h == d_x == 128
#define CH    16       // nodes per chunk per WAVE (8 float4 regs of x per lane)
#define SEG_PER_BLK 4  // one segment per wave, 4 waves per block
#define PROJ_ROWS 16   // h-rows per block in the proj GEMM
#define PROJ_BLOCKS (MSEG / PROJ_ROWS)            // 256
#define SEG_BLOCKS  ((NNODE + 255) / 256)         // 1024

// ============ DIAGNOSTIC ROUND ============
// Identical compute to round 3 (207.7 us), plus a SECOND attn launch writing
// to workspace scratch. attn is deterministic (no atomics), so the duplicate
// is bitwise-identical and correctness is unchanged. dur_us - 207.7 measures
// T_attn in situ (it never appears in the top-5 table, which is all 77 us
// harness fills). Pre-committed decision rule:
//   ~230 us -> attn at its 22 us compulsory-BW floor -> declare ROOFLINE
//   >=245   -> attn ~2x floor -> optimize attn next round
// ==========================================

// Kernel 1: fused prep. Blocks [0, PROJ_BLOCKS) compute proj = h @ a;
// blocks [PROJ_BLOCKS, ...) compute segment starts.
__global__ __launch_bounds__(256) void prep_kernel(
    const float* __restrict__ h, const float* __restrict__ a,
    float* __restrict__ proj,
    const int* __restrict__ seg, int* __restrict__ starts)
{
    __shared__ __align__(16) float a_lds[DDIM * DDIM];        // 64 KB
    __shared__ __align__(16) float h_lds[PROJ_ROWS * DDIM];   // 8 KB
    const int tid = threadIdx.x;

    if (blockIdx.x >= PROJ_BLOCKS) {
        // ---- segment starts (segment_ids is sorted) ----------------------
        const int i = (blockIdx.x - PROJ_BLOCKS) * 256 + tid;
        if (i >= NNODE) return;
        const int s = seg[i];
        const int prev = (i == 0) ? -1 : seg[i - 1];
        for (int g = prev + 1; g <= s; ++g) starts[g] = i;
        if (i == NNODE - 1)
            for (int g = s + 1; g <= MSEG; ++g) starts[g] = NNODE;
        return;
    }

    // ---- proj = h @ a: a staged once per block; 4 rows per thread --------
    const int g0 = blockIdx.x * PROJ_ROWS;
    const float4* a4  = (const float4*)a;
    float4*       al4 = (float4*)a_lds;
    #pragma unroll
    for (int j = 0; j < (DDIM * DDIM / 4) / 256; ++j)
        al4[j * 256 + tid] = a4[j * 256 + tid];
    const float4* h4  = (const float4*)(h + (size_t)g0 * DDIM);
    float4*       hl4 = (float4*)h_lds;
    #pragma unroll
    for (int j = 0; j < (PROJ_ROWS * DDIM / 4) / 256; ++j)
        hl4[j * 256 + tid] = h4[j * 256 + tid];
    __syncthreads();

    const int dp = tid & 63;            // col pair: cols 2dp, 2dp+1
    const int rh = tid >> 6;            // wave id: rows rh*4 .. rh*4+3
    const float2* al2 = (const float2*)a_lds;
    float2 p0 = make_float2(0.f, 0.f), p1 = make_float2(0.f, 0.f);
    float2 p2 = make_float2(0.f, 0.f), p3 = make_float2(0.f, 0.f);
    #pragma unroll 8
    for (int k = 0; k < DDIM; ++k) {
        const float2 av = al2[k * 64 + dp];   // read ONCE per k
        const float h0 = h_lds[(rh * 4 + 0) * DDIM + k];  // wave-uniform
        const float h1 = h_lds[(rh * 4 + 1) * DDIM + k];  // broadcasts
        const float h2 = h_lds[(rh * 4 + 2) * DDIM + k];
        const float h3 = h_lds[(rh * 4 + 3) * DDIM + k];
        p0.x += h0 * av.x; p0.y += h0 * av.y;
        p1.x += h1 * av.x; p1.y += h1 * av.y;
        p2.x += h2 * av.x; p2.y += h2 * av.y;
        p3.x += h3 * av.x; p3.y += h3 * av.y;
    }
    ((float2*)(proj + (size_t)(g0 + rh * 4 + 0) * DDIM))[dp] = p0;
    ((float2*)(proj + (size_t)(g0 + rh * 4 + 1) * DDIM))[dp] = p1;
    ((float2*)(proj + (size_t)(g0 + rh * 4 + 2) * DDIM))[dp] = p2;
    ((float2*)(proj + (size_t)(g0 + rh * 4 + 3) * DDIM))[dp] = p3;
}

// Kernel 2: WAVE-AUTONOMOUS attention (unchanged from round 3).
__global__ __launch_bounds__(256) void attn_seg_kernel(
    const float* __restrict__ x,
    const float* __restrict__ proj,
    const int*   __restrict__ starts,
    float*       __restrict__ out)
{
    const int tid = threadIdx.x;
    const int g   = blockIdx.x * SEG_PER_BLK + (tid >> 6);  // segment of this wave
    const int L   = tid & 63;
    const int l   = L & 15;                                 // dim quad owner
    const int r   = L >> 4;                                 // node slot 0..3

    const int start = starts[g];
    const int end   = starts[g + 1];
    float4* out4 = (float4*)out;

    if (start >= end) {                    // empty segment (wave-uniform)
        if (r == 0) {
            out4[(size_t)g * 32 + l]      = make_float4(0.f, 0.f, 0.f, 0.f);
            out4[(size_t)g * 32 + 16 + l] = make_float4(0.f, 0.f, 0.f, 0.f);
        }
        return;
    }

    const float4* __restrict__ x4p = (const float4*)x;
    const float4 pj0 = ((const float4*)proj)[(size_t)g * 32 + l];
    const float4 pj1 = ((const float4*)proj)[(size_t)g * 32 + 16 + l];

    float m_run = -INFINITY;               // wave-uniform
    float l_run = 0.f;                     // wave-uniform
    float4 acc0 = make_float4(0.f, 0.f, 0.f, 0.f); // dims 4l..4l+3
    float4 acc1 = make_float4(0.f, 0.f, 0.f, 0.f); // dims 64+4l..64+4l+3

    int cs  = start;
    int n_c = min(CH, end - cs);
    float4 xv0[4], xv1[4];
    #pragma unroll
    for (int p = 0; p < 4; ++p) {
        const int i = p * 4 + r;
        xv0[p] = make_float4(0.f, 0.f, 0.f, 0.f);
        xv1[p] = make_float4(0.f, 0.f, 0.f, 0.f);
        if (i < n_c) {
            const size_t base = (size_t)(cs + i) * 32 + l;
            xv0[p] = x4p[base];
            xv1[p] = x4p[base + 16];
        }
    }

    while (true) {
        // ---- scores: 8-dim partial, 16-lane xor-butterfly ----------------
        float sc[4];
        #pragma unroll
        for (int p = 0; p < 4; ++p) {
            float ps = xv0[p].x * pj0.x + xv0[p].y * pj0.y
                     + xv0[p].z * pj0.z + xv0[p].w * pj0.w
                     + xv1[p].x * pj1.x + xv1[p].y * pj1.y
                     + xv1[p].z * pj1.z + xv1[p].w * pj1.w;
            ps += __shfl_xor(ps, 1);
            ps += __shfl_xor(ps, 2);
            ps += __shfl_xor(ps, 4);
            ps += __shfl_xor(ps, 8);                   // all 16 lanes hold s
            sc[p] = (p * 4 + r < n_c) ? ps : -INFINITY;
        }
        // ---- wave-uniform chunk max --------------------------------------
        float mc = fmaxf(fmaxf(sc[0], sc[1]), fmaxf(sc[2], sc[3]));
        mc = fmaxf(mc, __shfl_xor(mc, 16));
        mc = fmaxf(mc, __shfl_xor(mc, 32));            // uniform across wave
        // ---- defer-max: rescale only if max jumped by > 30 ---------------
        if (mc - m_run > 30.f) {
            const float alpha = __expf(m_run - mc);    // 0 on first chunk
            l_run *= alpha;
            acc0.x *= alpha; acc0.y *= alpha; acc0.z *= alpha; acc0.w *= alpha;
            acc1.x *= alpha; acc1.y *= alpha; acc1.z *= alpha; acc1.w *= alpha;
            m_run = mc;
        }
        // ---- e = exp(s - m_run): lane-local, multiplies its OWN x --------
        float lsum = 0.f;
        #pragma unroll
        for (int p = 0; p < 4; ++p) {
            const bool valid = (p * 4 + r < n_c);
            const float e = valid ? __expf(sc[p] - m_run) : 0.f;
            lsum += e;
            acc0.x += e * xv0[p].x; acc0.y += e * xv0[p].y;
            acc0.z += e * xv0[p].z; acc0.w += e * xv0[p].w;
            acc1.x += e * xv1[p].x; acc1.y += e * xv1[p].y;
            acc1.z += e * xv1[p].z; acc1.w += e * xv1[p].w;
        }
        lsum += __shfl_xor(lsum, 16);                  // rows r and r^1
        lsum += __shfl_xor(lsum, 32);                  // + rows r^2, r^3
        l_run += lsum;                                 // uniform total

        cs += CH;
        if (cs >= end) break;
        n_c = min(CH, end - cs);
        #pragma unroll
        for (int p = 0; p < 4; ++p) {
            const int i = p * 4 + r;
            xv0[p] = make_float4(0.f, 0.f, 0.f, 0.f);
            xv1[p] = make_float4(0.f, 0.f, 0.f, 0.f);
            if (i < n_c) {
                const size_t base = (size_t)(cs + i) * 32 + l;
                xv0[p] = x4p[base];
                xv1[p] = x4p[base + 16];
            }
        }
    }

    // ---- epilogue: sum acc over the 4 node slots, all in registers -------
    acc0.x += __shfl_xor(acc0.x, 16); acc0.y += __shfl_xor(acc0.y, 16);
    acc0.z += __shfl_xor(acc0.z, 16); acc0.w += __shfl_xor(acc0.w, 16);
    acc1.x += __shfl_xor(acc1.x, 16); acc1.y += __shfl_xor(acc1.y, 16);
    acc1.z += __shfl_xor(acc1.z, 16); acc1.w += __shfl_xor(acc1.w, 16);
    acc0.x += __shfl_xor(acc0.x, 32); acc0.y += __shfl_xor(acc0.y, 32);
    acc0.z += __shfl_xor(acc0.z, 32); acc0.w += __shfl_xor(acc0.w, 32);
    acc1.x += __shfl_xor(acc1.x, 32); acc1.y += __shfl_xor(acc1.y, 32);
    acc1.z += __shfl_xor(acc1.z, 32); acc1.w += __shfl_xor(acc1.w, 32);

    if (r == 0) {
        const float inv = 1.f / l_run;
        out4[(size_t)g * 32 + l] =
            make_float4(acc0.x * inv, acc0.y * inv, acc0.z * inv, acc0.w * inv);
        out4[(size_t)g * 32 + 16 + l] =
            make_float4(acc1.x * inv, acc1.y * inv, acc1.z * inv, acc1.w * inv);
    }
}

extern "C" void kernel_launch(void* const* d_in, const int* in_sizes, int n_in,
                              void* d_out, int out_size, void* d_ws, size_t ws_size,
                              hipStream_t stream) {
    const float* h   = (const float*)d_in[0];   // (M, DH)
    const float* x   = (const float*)d_in[1];   // (N, DX)
    const float* a   = (const float*)d_in[2];   // (DH, DX)
    const int*   seg = (const int*)  d_in[3];   // (N,) sorted
    float* out = (float*)d_out;                 // (M, DX)

    int*   starts = (int*)d_ws;                             // (MSEG+1,)
    float* proj   = (float*)((char*)d_ws + 32768);          // (MSEG, DDIM)
    // diagnostic scratch output, far from everything else (ws >= 512 MB
    // per the 536 MB harness poison-fill of this buffer)
    float* out_diag = (float*)((char*)d_ws + (64u << 20));  // (MSEG, DDIM)

    prep_kernel<<<PROJ_BLOCKS + SEG_BLOCKS, 256, 0, stream>>>(h, a, proj, seg, starts);
    attn_seg_kernel<<<MSEG / SEG_PER_BLK, 256, 0, stream>>>(x, proj, starts, out);
    // DIAGNOSTIC duplicate: dur_us - 207.7 == T_attn (in situ)
    attn_seg_kernel<<<MSEG / SEG_PER_BLK, 256, 0, stream>>>(x, proj, starts, out_diag);
}

// Round 5
// 206.335 us; speedup vs baseline: 1.1205x; 1.1205x over previous
//
#include <hip/hip_runtime.h>
#include <math.h>

// Problem constants (from reference)
#define MSEG  4096     // number of graphs / segments
#define NNODE 262144   // total nodes
#define DDIM  128      // d_h == d_x == 128
#define CH    16       // nodes per chunk per WAVE (8 float4 regs of x per lane)
#define SEG_PER_BLK 4  // one segment per wave, 4 waves per block
#define PROJ_ROWS 16   // h-rows per block in the proj GEMM
#define PROJ_BLOCKS (MSEG / PROJ_ROWS)            // 256
#define SEG_BLOCKS  ((NNODE + 255) / 256)         // 1024

// FINAL (round-3 proven source, 207.7 us; round-4 diagnostic removed).
// Measured decomposition: ~155 us harness poison-fills (2x536 MB @87% peak)
// + 23.5 us attn (measured in situ round 4; 87-89% of the 6.3 TB/s ceiling
// for its 128 MB compulsory x-read) + ~5 us prep + ~24 us harness memset
// train / launch gaps. The kernel-controllable slice is at its
// compulsory-traffic roofline.

// Kernel 1: fused prep. Blocks [0, PROJ_BLOCKS) compute proj = h @ a;
// blocks [PROJ_BLOCKS, ...) compute segment starts.
__global__ __launch_bounds__(256) void prep_kernel(
    const float* __restrict__ h, const float* __restrict__ a,
    float* __restrict__ proj,
    const int* __restrict__ seg, int* __restrict__ starts)
{
    __shared__ __align__(16) float a_lds[DDIM * DDIM];        // 64 KB
    __shared__ __align__(16) float h_lds[PROJ_ROWS * DDIM];   // 8 KB
    const int tid = threadIdx.x;

    if (blockIdx.x >= PROJ_BLOCKS) {
        // ---- segment starts (segment_ids is sorted) ----------------------
        const int i = (blockIdx.x - PROJ_BLOCKS) * 256 + tid;
        if (i >= NNODE) return;
        const int s = seg[i];
        const int prev = (i == 0) ? -1 : seg[i - 1];
        for (int g = prev + 1; g <= s; ++g) starts[g] = i;
        if (i == NNODE - 1)
            for (int g = s + 1; g <= MSEG; ++g) starts[g] = NNODE;
        return;
    }

    // ---- proj = h @ a: a staged once per block; 4 rows per thread --------
    const int g0 = blockIdx.x * PROJ_ROWS;
    const float4* a4  = (const float4*)a;
    float4*       al4 = (float4*)a_lds;
    #pragma unroll
    for (int j = 0; j < (DDIM * DDIM / 4) / 256; ++j)
        al4[j * 256 + tid] = a4[j * 256 + tid];
    const float4* h4  = (const float4*)(h + (size_t)g0 * DDIM);
    float4*       hl4 = (float4*)h_lds;
    #pragma unroll
    for (int j = 0; j < (PROJ_ROWS * DDIM / 4) / 256; ++j)
        hl4[j * 256 + tid] = h4[j * 256 + tid];
    __syncthreads();

    const int dp = tid & 63;            // col pair: cols 2dp, 2dp+1
    const int rh = tid >> 6;            // wave id: rows rh*4 .. rh*4+3
    const float2* al2 = (const float2*)a_lds;
    float2 p0 = make_float2(0.f, 0.f), p1 = make_float2(0.f, 0.f);
    float2 p2 = make_float2(0.f, 0.f), p3 = make_float2(0.f, 0.f);
    #pragma unroll 8
    for (int k = 0; k < DDIM; ++k) {
        const float2 av = al2[k * 64 + dp];   // read ONCE per k
        const float h0 = h_lds[(rh * 4 + 0) * DDIM + k];  // wave-uniform
        const float h1 = h_lds[(rh * 4 + 1) * DDIM + k];  // broadcasts
        const float h2 = h_lds[(rh * 4 + 2) * DDIM + k];
        const float h3 = h_lds[(rh * 4 + 3) * DDIM + k];
        p0.x += h0 * av.x; p0.y += h0 * av.y;
        p1.x += h1 * av.x; p1.y += h1 * av.y;
        p2.x += h2 * av.x; p2.y += h2 * av.y;
        p3.x += h3 * av.x; p3.y += h3 * av.y;
    }
    ((float2*)(proj + (size_t)(g0 + rh * 4 + 0) * DDIM))[dp] = p0;
    ((float2*)(proj + (size_t)(g0 + rh * 4 + 1) * DDIM))[dp] = p1;
    ((float2*)(proj + (size_t)(g0 + rh * 4 + 2) * DDIM))[dp] = p2;
    ((float2*)(proj + (size_t)(g0 + rh * 4 + 3) * DDIM))[dp] = p3;
}

// Kernel 2: WAVE-AUTONOMOUS attention. One wave = one segment; 4 independent
// waves per block; NO LDS, NO __syncthreads.
// Dim mapping: lane l = L&15 owns dims [4l,4l+4) and [64+4l,64+4l+4), so
// every global_load_dwordx4 covers a contiguous 256 B per 16-lane group.
// r = L>>4 is the node slot; chunk = 16 nodes (node i = p*4 + r).
// Score reduce: xor-butterfly {1,2,4,8} -> all 16 lanes hold the node score,
// so e*x needs no broadcast. Wave-uniform max/sum: xor{16,32}.
// Online softmax with defer-max (THR=30).
__global__ __launch_bounds__(256) void attn_seg_kernel(
    const float* __restrict__ x,
    const float* __restrict__ proj,
    const int*   __restrict__ starts,
    float*       __restrict__ out)
{
    const int tid = threadIdx.x;
    const int g   = blockIdx.x * SEG_PER_BLK + (tid >> 6);  // segment of this wave
    const int L   = tid & 63;
    const int l   = L & 15;                                 // dim quad owner
    const int r   = L >> 4;                                 // node slot 0..3

    const int start = starts[g];
    const int end   = starts[g + 1];
    float4* out4 = (float4*)out;

    if (start >= end) {                    // empty segment (wave-uniform)
        if (r == 0) {
            out4[(size_t)g * 32 + l]      = make_float4(0.f, 0.f, 0.f, 0.f);
            out4[(size_t)g * 32 + 16 + l] = make_float4(0.f, 0.f, 0.f, 0.f);
        }
        return;
    }

    const float4* __restrict__ x4p = (const float4*)x;
    const float4 pj0 = ((const float4*)proj)[(size_t)g * 32 + l];
    const float4 pj1 = ((const float4*)proj)[(size_t)g * 32 + 16 + l];

    float m_run = -INFINITY;               // wave-uniform
    float l_run = 0.f;                     // wave-uniform
    float4 acc0 = make_float4(0.f, 0.f, 0.f, 0.f); // dims 4l..4l+3
    float4 acc1 = make_float4(0.f, 0.f, 0.f, 0.f); // dims 64+4l..64+4l+3

    int cs  = start;
    int n_c = min(CH, end - cs);
    float4 xv0[4], xv1[4];
    #pragma unroll
    for (int p = 0; p < 4; ++p) {
        const int i = p * 4 + r;
        xv0[p] = make_float4(0.f, 0.f, 0.f, 0.f);
        xv1[p] = make_float4(0.f, 0.f, 0.f, 0.f);
        if (i < n_c) {
            const size_t base = (size_t)(cs + i) * 32 + l;
            xv0[p] = x4p[base];
            xv1[p] = x4p[base + 16];
        }
    }

    while (true) {
        // ---- scores: 8-dim partial, 16-lane xor-butterfly ----------------
        float sc[4];
        #pragma unroll
        for (int p = 0; p < 4; ++p) {
            float ps = xv0[p].x * pj0.x + xv0[p].y * pj0.y
                     + xv0[p].z * pj0.z + xv0[p].w * pj0.w
                     + xv1[p].x * pj1.x + xv1[p].y * pj1.y
                     + xv1[p].z * pj1.z + xv1[p].w * pj1.w;
            ps += __shfl_xor(ps, 1);
            ps += __shfl_xor(ps, 2);
            ps += __shfl_xor(ps, 4);
            ps += __shfl_xor(ps, 8);                   // all 16 lanes hold s
            sc[p] = (p * 4 + r < n_c) ? ps : -INFINITY;
        }
        // ---- wave-uniform chunk max --------------------------------------
        float mc = fmaxf(fmaxf(sc[0], sc[1]), fmaxf(sc[2], sc[3]));
        mc = fmaxf(mc, __shfl_xor(mc, 16));
        mc = fmaxf(mc, __shfl_xor(mc, 32));            // uniform across wave
        // ---- defer-max: rescale only if max jumped by > 30 ---------------
        if (mc - m_run > 30.f) {
            const float alpha = __expf(m_run - mc);    // 0 on first chunk
            l_run *= alpha;
            acc0.x *= alpha; acc0.y *= alpha; acc0.z *= alpha; acc0.w *= alpha;
            acc1.x *= alpha; acc1.y *= alpha; acc1.z *= alpha; acc1.w *= alpha;
            m_run = mc;
        }
        // ---- e = exp(s - m_run): lane-local, multiplies its OWN x --------
        float lsum = 0.f;
        #pragma unroll
        for (int p = 0; p < 4; ++p) {
            const bool valid = (p * 4 + r < n_c);
            const float e = valid ? __expf(sc[p] - m_run) : 0.f;
            lsum += e;
            acc0.x += e * xv0[p].x; acc0.y += e * xv0[p].y;
            acc0.z += e * xv0[p].z; acc0.w += e * xv0[p].w;
            acc1.x += e * xv1[p].x; acc1.y += e * xv1[p].y;
            acc1.z += e * xv1[p].z; acc1.w += e * xv1[p].w;
        }
        lsum += __shfl_xor(lsum, 16);                  // rows r and r^1
        lsum += __shfl_xor(lsum, 32);                  // + rows r^2, r^3
        l_run += lsum;                                 // uniform total

        cs += CH;
        if (cs >= end) break;
        n_c = min(CH, end - cs);
        #pragma unroll
        for (int p = 0; p < 4; ++p) {
            const int i = p * 4 + r;
            xv0[p] = make_float4(0.f, 0.f, 0.f, 0.f);
            xv1[p] = make_float4(0.f, 0.f, 0.f, 0.f);
            if (i < n_c) {
                const size_t base = (size_t)(cs + i) * 32 + l;
                xv0[p] = x4p[base];
                xv1[p] = x4p[base + 16];
            }
        }
    }

    // ---- epilogue: sum acc over the 4 node slots, all in registers -------
    acc0.x += __shfl_xor(acc0.x, 16); acc0.y += __shfl_xor(acc0.y, 16);
    acc0.z += __shfl_xor(acc0.z, 16); acc0.w += __shfl_xor(acc0.w, 16);
    acc1.x += __shfl_xor(acc1.x, 16); acc1.y += __shfl_xor(acc1.y, 16);
    acc1.z += __shfl_xor(acc1.z, 16); acc1.w += __shfl_xor(acc1.w, 16);
    acc0.x += __shfl_xor(acc0.x, 32); acc0.y += __shfl_xor(acc0.y, 32);
    acc0.z += __shfl_xor(acc0.z, 32); acc0.w += __shfl_xor(acc0.w, 32);
    acc1.x += __shfl_xor(acc1.x, 32); acc1.y += __shfl_xor(acc1.y, 32);
    acc1.z += __shfl_xor(acc1.z, 32); acc1.w += __shfl_xor(acc1.w, 32);

    if (r == 0) {
        const float inv = 1.f / l_run;
        out4[(size_t)g * 32 + l] =
            make_float4(acc0.x * inv, acc0.y * inv, acc0.z * inv, acc0.w * inv);
        out4[(size_t)g * 32 + 16 + l] =
            make_float4(acc1.x * inv, acc1.y * inv, acc1.z * inv, acc1.w * inv);
    }
}

extern "C" void kernel_launch(void* const* d_in, const int* in_sizes, int n_in,
                              void* d_out, int out_size, void* d_ws, size_t ws_size,
                              hipStream_t stream) {
    const float* h   = (const float*)d_in[0];   // (M, DH)
    const float* x   = (const float*)d_in[1];   // (N, DX)
    const float* a   = (const float*)d_in[2];   // (DH, DX)
    const int*   seg = (const int*)  d_in[3];   // (N,) sorted
    float* out = (float*)d_out;                 // (M, DX)

    int*   starts = (int*)d_ws;                             // (MSEG+1,)
    float* proj   = (float*)((char*)d_ws + 32768);          // (MSEG, DDIM)

    prep_kernel<<<PROJ_BLOCKS + SEG_BLOCKS, 256, 0, stream>>>(h, a, proj, seg, starts);
    attn_seg_kernel<<<MSEG / SEG_PER_BLK, 256, 0, stream>>>(x, proj, starts, out);
}